// Round 16
// baseline (238.023 us; speedup 1.0000x reference)
//
#include <hip/hip_runtime.h>
#include <hip/hip_bf16.h>
#include <math.h>

#define HIDDEN 768
#define NHEADS 12
#define HDIM   64
#define NTOK   1024   // 32*32
#define BATCH  8
#define CIN    256
#define M_ALL  (BATCH * NTOK)   // 8192
#define LSTR   72               // padded stride for P (register-sourced writes)

typedef __hip_bfloat16 bf16;
typedef short frag8 __attribute__((ext_vector_type(8)));   // 8 bf16 = 4 VGPRs
typedef short s16x4 __attribute__((ext_vector_type(4)));
typedef unsigned int u32x2 __attribute__((ext_vector_type(2)));
typedef float f32x4 __attribute__((ext_vector_type(4)));

#define GL2LDS(gp, lp) \
    __builtin_amdgcn_global_load_lds((const __attribute__((address_space(1))) void*)(gp), \
                                     (__attribute__((address_space(3))) void*)(lp), 16, 0, 0)

__device__ __forceinline__ short f2bs(float x){
    union { bf16 h; short s; } u; u.h = __float2bfloat16(x); return u.s;
}

// Gaussian weight (inference buffers mu=0 sigma=1)
__device__ __forceinline__ float gaussw(float x){
    float x2 = x * x;
    return (__expf(-x2 / 0.50001f) + __expf(-x2 / 2.00001f) + __expf(-x2 / 8.00001f)) * (1.0f / 3.0f);
}

// ------------------------------------------------------------ prep kernel
// blocks [0,48): proj_w transpose (256x768 -> wtp[768][256])
// blocks [48,560): feat transpose per batch ([256][1024] -> featT[b][1024][256])
// blocks [560,816): PE table precompute (1024x768 f32)
__global__ __launch_bounds__(256) void prep_all(
    const float* __restrict__ proj_w, const float* __restrict__ feat,
    short* __restrict__ wtp, short* __restrict__ featT, float* __restrict__ pe)
{
    const int blk = blockIdx.x;
    const int tid = threadIdx.x;
    if (blk >= 560) {
        const float kfac = -9.210340371976184f / 768.0f;  // -ln(10000)/HIDDEN
        int e0 = (blk - 560) * 3072 + tid;
        #pragma unroll
        for (int it = 0; it < 12; it++) {
            int e = e0 + it * 256;
            int n = e / 768;
            int d = e - n * 768;
            float ang = (float)n * expf((float)(2 * (d >> 1)) * kfac);
            pe[e] = (d & 1) ? cosf(ang) : sinf(ang);
        }
        return;
    }
    __shared__ short t[64][65];
    const float* W; short* WT; int K, N, k0, n0;
    if (blk < 48) {
        W = proj_w; WT = wtp;
        K = CIN; N = HIDDEN; k0 = (blk / 12) * 64; n0 = (blk % 12) * 64;
    } else {
        int rem = blk - 48;               // 512 = 8 b x 64 (4x16)
        int b = rem / 64; rem %= 64;
        W = feat + (size_t)b * CIN * NTOK; WT = featT + (size_t)b * NTOK * CIN;
        K = CIN; N = NTOK; k0 = (rem / 16) * 64; n0 = (rem % 16) * 64;
    }
    #pragma unroll
    for (int it = 0; it < 16; it++) {
        int e = tid + 256 * it;
        int kk = e / 64, nn = e % 64;
        t[kk][nn] = f2bs(W[(size_t)(k0 + kk) * N + n0 + nn]);
    }
    __syncthreads();
    #pragma unroll
    for (int it = 0; it < 16; it++) {
        int e = tid + 256 * it;
        int nn = e / 64, kk = e % 64;
        WT[(size_t)(n0 + nn) * K + k0 + kk] = t[kk][nn];
    }
}

// ------------------------------------------------------------ fused tokens GEMM + weight transposes
// blocks [0,768): tokens = featT @ wtp^T + bias + PE-table (64x128 tiles, K=256)
// blocks [768,1344): wq/wk/wv/wo transposes
__global__ __launch_bounds__(256) void tokens_wprep(
    const short* __restrict__ A, const short* __restrict__ WT,
    const float* __restrict__ bias, const float* __restrict__ pe,
    short* __restrict__ outv,
    const float* __restrict__ wq, const float* __restrict__ wk,
    const float* __restrict__ wv, const float* __restrict__ wo,
    short* __restrict__ wtqkv)
{
    const int blk = blockIdx.x;
    const int tid = threadIdx.x;
    if (blk >= 768) {
        __shared__ short t[64][65];
        int bw = blk - 768;
        int p = bw / 144, rem = bw % 144;
        const float* srcs[4] = {wq, wk, wv, wo};
        const float* W = srcs[p];
        short* WTo = wtqkv + (size_t)p * HIDDEN * HIDDEN;
        int k0 = (rem / 12) * 64, n0 = (rem % 12) * 64;
        #pragma unroll
        for (int it = 0; it < 16; it++) {
            int e = tid + 256 * it;
            int kk = e / 64, nn = e % 64;
            t[kk][nn] = f2bs(W[(size_t)(k0 + kk) * HIDDEN + n0 + nn]);
        }
        __syncthreads();
        #pragma unroll
        for (int it = 0; it < 16; it++) {
            int e = tid + 256 * it;
            int nn = e / 64, kk = e % 64;
            WTo[(size_t)(n0 + nn) * HIDDEN + k0 + kk] = t[kk][nn];
        }
        return;
    }
    __shared__ short Al[64 * 32];
    __shared__ short Bl[128 * 32];
    const int m0   = (blk & 127) * 64;
    const int n0   = (blk >> 7) * 128;
    const int lane = tid & 63, wid = tid >> 6;
    const int wn   = wid * 32;
    const int l16  = lane & 15, quad = lane >> 4;

    const int sr  = lane >> 2;
    const int ssg = (lane & 3) ^ ((sr >> 1) & 3);
    const int fsw = (l16 >> 1) & 3;

    const f32x4 z4 = {0.f, 0.f, 0.f, 0.f};
    f32x4 acc[4][2];
    #pragma unroll
    for (int i = 0; i < 4; i++)
        #pragma unroll
        for (int j = 0; j < 2; j++) acc[i][j] = z4;

    const int K = CIN;
    for (int k0 = 0; k0 < K; k0 += 32) {
        GL2LDS(A + (size_t)(m0 + wid * 16 + sr) * K + k0 + ssg * 8, &Al[(wid * 16) * 32]);
        #pragma unroll
        for (int t = 0; t < 2; t++) {
            int rbase = wid * 32 + t * 16;
            GL2LDS(WT + (size_t)(n0 + rbase + sr) * K + k0 + ssg * 8, &Bl[rbase * 32]);
        }
        __syncthreads();
        frag8 af[4], bfr[2];
        #pragma unroll
        for (int i = 0; i < 4; i++)
            af[i]  = *(const frag8*)&Al[(i * 16 + l16) * 32 + ((quad ^ fsw) * 8)];
        #pragma unroll
        for (int j = 0; j < 2; j++)
            bfr[j] = *(const frag8*)&Bl[(wn + j * 16 + l16) * 32 + ((quad ^ fsw) * 8)];
        #pragma unroll
        for (int i = 0; i < 4; i++)
            #pragma unroll
            for (int j = 0; j < 2; j++)
                acc[i][j] = __builtin_amdgcn_mfma_f32_16x16x32_bf16(af[i], bfr[j], acc[i][j], 0, 0, 0);
        __syncthreads();
    }

    #pragma unroll
    for (int i = 0; i < 4; i++) {
        #pragma unroll
        for (int r = 0; r < 4; r++) {
            int m = m0 + i * 16 + quad * 4 + r;
            int n_tok = m & (NTOK - 1);
            #pragma unroll
            for (int j = 0; j < 2; j++) {
                int col = n0 + wn + j * 16 + l16;
                float val = acc[i][j][r] + bias[col] + pe[n_tok * HIDDEN + col];
                outv[(size_t)m * HIDDEN + col] = f2bs(val);
            }
        }
    }
}

// ------------------------------------------------------------ V transpose (bf16 -> bf16)
// v [8192][768] -> vT [B*NH][64][1024]   (vT[bh][d][n])
// extra blocks (blockIdx.y == 96): precompute gauss weights g[b][n] from I
__global__ __launch_bounds__(256) void transpose_v(
    const short* __restrict__ v, short* __restrict__ vT,
    const float* __restrict__ I, float* __restrict__ g)
{
    if (blockIdx.y == BATCH * NHEADS) {
        int idx = blockIdx.x * 512 + threadIdx.x * 2;
        g[idx]     = gaussw(I[idx]);
        g[idx + 1] = gaussw(I[idx + 1]);
        return;
    }
    __shared__ short t[64][65];
    const int nt = blockIdx.x;
    const int bh = blockIdx.y;
    const int b = bh / NHEADS, h = bh % NHEADS;
    const int tid = threadIdx.x;
    #pragma unroll
    for (int it = 0; it < 16; it++) {
        int e = tid + 256 * it;
        int rr = e / 64, cc = e % 64;
        t[rr][cc] = v[(size_t)(b * NTOK + nt * 64 + rr) * HIDDEN + h * HDIM + cc];
    }
    __syncthreads();
    #pragma unroll
    for (int it = 0; it < 16; it++) {
        int e = tid + 256 * it;
        int c2 = e / 64, r2 = e % 64;
        vT[((size_t)bh * HDIM + c2) * NTOK + nt * 64 + r2] = t[r2][c2];
    }
}

// ------------------------------------------------------------ MFMA GEMM 128x128 (QKV)
// BK=32, DOUBLE-BUFFERED (verified round 12/13). LDS 32 KB.
__global__ __launch_bounds__(256) void gemm_mfma128(
    const short* __restrict__ A, const short* __restrict__ WT0, long wt_z,
    const float* __restrict__ b0, const float* __restrict__ b1, const float* __restrict__ b2,
    short* o0, short* o1, short* o2, int K)
{
    __shared__ short Al[2][128 * 32];
    __shared__ short Bl[2][128 * 32];
    const int z = blockIdx.z;
    const short* WT  = WT0 + (size_t)z * wt_z;
    const float* bias = (z == 0) ? b0 : (z == 1) ? b1 : b2;
    short* outv       = (z == 0) ? o0 : (z == 1) ? o1 : o2;

    const int tid  = threadIdx.x;
    const int m0   = blockIdx.x * 128;
    const int n0   = blockIdx.y * 128;
    const int lane = tid & 63, wid = tid >> 6;
    const int wm   = (wid >> 1) * 64, wn = (wid & 1) * 64;
    const int l16  = lane & 15, quad = lane >> 4;

    const int sr  = lane >> 2;
    const int ssg = (lane & 3) ^ ((sr >> 1) & 3);
    const int fsw = (l16 >> 1) & 3;

    const f32x4 z4 = {0.f, 0.f, 0.f, 0.f};
    f32x4 acc[4][4];
    #pragma unroll
    for (int i = 0; i < 4; i++)
        #pragma unroll
        for (int j = 0; j < 4; j++) acc[i][j] = z4;

    // prologue: stage K-step 0 into buf 0
    #pragma unroll
    for (int t = 0; t < 2; t++) {
        int rbase = wid * 32 + t * 16;
        int r = rbase + sr;
        GL2LDS(A  + (size_t)(m0 + r) * K + ssg * 8, &Al[0][rbase * 32]);
        GL2LDS(WT + (size_t)(n0 + r) * K + ssg * 8, &Bl[0][rbase * 32]);
    }
    __syncthreads();

    const int NSTEP = K / 32;
    for (int ks = 0; ks < NSTEP; ks++) {
        const int cur = ks & 1;
        if (ks < NSTEP - 1) {
            int k0n = (ks + 1) * 32;
            #pragma unroll
            for (int t = 0; t < 2; t++) {
                int rbase = wid * 32 + t * 16;
                int r = rbase + sr;
                GL2LDS(A  + (size_t)(m0 + r) * K + k0n + ssg * 8, &Al[cur ^ 1][rbase * 32]);
                GL2LDS(WT + (size_t)(n0 + r) * K + k0n + ssg * 8, &Bl[cur ^ 1][rbase * 32]);
            }
        }
        frag8 af[4], bfr[4];
        #pragma unroll
        for (int i = 0; i < 4; i++)
            af[i]  = *(const frag8*)&Al[cur][(wm + i * 16 + l16) * 32 + ((quad ^ fsw) * 8)];
        #pragma unroll
        for (int j = 0; j < 4; j++)
            bfr[j] = *(const frag8*)&Bl[cur][(wn + j * 16 + l16) * 32 + ((quad ^ fsw) * 8)];
        #pragma unroll
        for (int i = 0; i < 4; i++)
            #pragma unroll
            for (int j = 0; j < 4; j++)
                acc[i][j] = __builtin_amdgcn_mfma_f32_16x16x32_bf16(af[i], bfr[j], acc[i][j], 0, 0, 0);
        __syncthreads();   // all waves done reading buf[cur]; prefetch into buf^1 drained
    }

    #pragma unroll
    for (int i = 0; i < 4; i++) {
        #pragma unroll
        for (int r = 0; r < 4; r++) {
            int m = m0 + wm + i * 16 + quad * 4 + r;
            #pragma unroll
            for (int j = 0; j < 4; j++) {
                int col = n0 + wn + j * 16 + l16;
                outv[(size_t)m * HIDDEN + col] = f2bs(acc[i][j][r] + bias[col]);
            }
        }
    }
}

// ------------------------------------------------------------ MFMA GEMM 64x128 (final projection)
// out f32 = acc + bias
__global__ __launch_bounds__(256) void gemm_mfma64f(
    const short* __restrict__ A, const short* __restrict__ WT,
    const float* __restrict__ bias, float* __restrict__ outv, int K)
{
    __shared__ short Al[64 * 32];
    __shared__ short Bl[128 * 32];
    const int tid  = threadIdx.x;
    const int m0   = blockIdx.x * 64;
    const int n0   = blockIdx.y * 128;
    const int lane = tid & 63, wid = tid >> 6;
    const int wn   = wid * 32;
    const int l16  = lane & 15, quad = lane >> 4;

    const int sr  = lane >> 2;
    const int ssg = (lane & 3) ^ ((sr >> 1) & 3);
    const int fsw = (l16 >> 1) & 3;

    const f32x4 z4 = {0.f, 0.f, 0.f, 0.f};
    f32x4 acc[4][2];
    #pragma unroll
    for (int i = 0; i < 4; i++)
        #pragma unroll
        for (int j = 0; j < 2; j++) acc[i][j] = z4;

    for (int k0 = 0; k0 < K; k0 += 32) {
        GL2LDS(A + (size_t)(m0 + wid * 16 + sr) * K + k0 + ssg * 8, &Al[(wid * 16) * 32]);
        #pragma unroll
        for (int t = 0; t < 2; t++) {
            int rbase = wid * 32 + t * 16;
            GL2LDS(WT + (size_t)(n0 + rbase + sr) * K + k0 + ssg * 8, &Bl[rbase * 32]);
        }
        __syncthreads();
        frag8 af[4], bfr[2];
        #pragma unroll
        for (int i = 0; i < 4; i++)
            af[i]  = *(const frag8*)&Al[(i * 16 + l16) * 32 + ((quad ^ fsw) * 8)];
        #pragma unroll
        for (int j = 0; j < 2; j++)
            bfr[j] = *(const frag8*)&Bl[(wn + j * 16 + l16) * 32 + ((quad ^ fsw) * 8)];
        #pragma unroll
        for (int i = 0; i < 4; i++)
            #pragma unroll
            for (int j = 0; j < 2; j++)
                acc[i][j] = __builtin_amdgcn_mfma_f32_16x16x32_bf16(af[i], bfr[j], acc[i][j], 0, 0, 0);
        __syncthreads();
    }

    #pragma unroll
    for (int i = 0; i < 4; i++) {
        #pragma unroll
        for (int r = 0; r < 4; r++) {
            int m = m0 + i * 16 + quad * 4 + r;
            #pragma unroll
            for (int j = 0; j < 2; j++) {
                int col = n0 + wn + j * 16 + l16;
                outv[(size_t)m * HIDDEN + col] = acc[i][j][r] + bias[col];
            }
        }
    }
}

// ------------------------------------------------------------- MFMA flash attention v6 (= v5 + Pl XOR swizzle)
// ONE change vs verified v5: Pl column offset XOR-swizzled per row
// (col ^= (row&7)*8 shorts). SQ_LDS_BANK_CONFLICT measured 2.36M cyc/dispatch;
// Ks/Vt use the conflict-free fsw pattern and GL2LDS writes can't conflict ->
// conflicts attributed to Pl (LSTR=72 -> 144B row stride = 4-bank step).
// Writer (b64, cols mult-of-4 in [0,64)) and reader (b128, cols mult-of-8,
// 16B-aligned) apply the SAME involution -> data mapping unchanged, alignment
// preserved.  LDS: P 18432 + 2x8192 (K) + 2x8192 (V) = 51200 B -> 3 blocks/CU.
__global__ __launch_bounds__(256, 3) void attn_mfma(
    const short* __restrict__ q, const short* __restrict__ k, const short* __restrict__ vT,
    const float* __restrict__ g, const float* __restrict__ lam_p, short* __restrict__ out)
{
    __shared__ short Pl[128 * LSTR];   // P tile, wave-private rows, swizzled cols
    __shared__ short Ks[2][64 * 64];
    __shared__ short Vt[2][64 * 64];

    const int tid  = threadIdx.x;
    const int lin  = blockIdx.x;
    const int xcd  = lin & 7, slot = lin >> 3;
    const int b    = xcd;
    const int h    = slot >> 3;
    const int qt   = slot & 7;
    const float L2E  = 1.4426950408889634f;
    const float lam2 = lam_p[0] * L2E;
    const float scl  = 0.125f * L2E;
    const int lane = tid & 63, wave = tid >> 6;
    const int l16  = lane & 15, quad = lane >> 4;

    const int sr   = lane >> 3;          // staging row within 8-row group
    const int slin = lane & 7;           // dest 16B segment
    const int ssg  = slin ^ sr;          // swizzled source segment
    const int fsw  = l16 & 7;            // frag-read swizzle

    const size_t kb  = (size_t)b * NTOK * HIDDEN + h * HDIM;
    const size_t vtb = (size_t)(b * NHEADS + h) * HDIM * NTOK;
    const float* gk  = g + b * NTOK;

    // Pl row for this lane (both store and ap-read use the same row) + swizzle
    const int prow = wave * 32 + l16;           // +half*16 added per use
    // Q fragments direct from global (B-operand: col = q row, kdim contiguous)
    frag8 aq[2][2];
    #pragma unroll
    for (int half = 0; half < 2; half++)
        #pragma unroll
        for (int kc = 0; kc < 2; kc++)
            aq[half][kc] = *(const frag8*)&q[(size_t)(b * NTOK + qt * 128 + wave * 32 + half * 16 + l16) * HIDDEN
                                             + h * HDIM + kc * 32 + quad * 8];
    // q-side gaussian (x lam2), one per half (q = half*16 + l16)
    float gq[2];
    #pragma unroll
    for (int half = 0; half < 2; half++)
        gq[half] = lam2 * gk[qt * 128 + wave * 32 + half * 16 + l16];

    // prologue: stage tile 0 into buf 0
    #pragma unroll
    for (int t = 0; t < 2; t++) {
        int rbase = wave * 16 + t * 8;
        int r = rbase + sr;
        GL2LDS(k  + kb  + (size_t)r * HIDDEN + ssg * 8,  &Ks[0][rbase * 64]);
        GL2LDS(vT + vtb + (size_t)r * NTOK + ssg * 8,    &Vt[0][rbase * 64]);
    }
    __syncthreads();

    const f32x4 z4 = {0.f, 0.f, 0.f, 0.f};
    f32x4 o_acc[2][4];
    #pragma unroll
    for (int half = 0; half < 2; half++)
        #pragma unroll
        for (int d = 0; d < 4; d++) o_acc[half][d] = z4;
    float l_run[2] = {0.f, 0.f};

    for (int jt = 0; jt < 16; jt++) {
        const int cur = jt & 1;
        // k-side gaussian for THIS tile, issued FIRST: the exp-phase consumption
        // then needs only vmcnt(4) (the 4 newer GL2LDS below stay in flight).
        f32x4 gk4[4];
        #pragma unroll
        for (int t4 = 0; t4 < 4; t4++)
            gk4[t4] = *(const f32x4*)&gk[jt * 64 + t4 * 16 + quad * 4];
        __builtin_amdgcn_sched_barrier(0);   // pin: g-loads issue before prefetch
        // prefetch next tile into the other buffer (overlaps with compute below)
        if (jt < 15) {
            #pragma unroll
            for (int t = 0; t < 2; t++) {
                int rbase = wave * 16 + t * 8;
                int r = rbase + sr;
                GL2LDS(k  + kb  + (size_t)((jt + 1) * 64 + r) * HIDDEN + ssg * 8, &Ks[cur ^ 1][rbase * 64]);
                GL2LDS(vT + vtb + (size_t)r * NTOK + (jt + 1) * 64 + ssg * 8,     &Vt[cur ^ 1][rbase * 64]);
            }
        }

        // S^T = K.Q^T : lane holds k = t4*16 + quad*4 + r, q = half*16 + l16
        float p[2][4][4];
        #pragma unroll
        for (int t4 = 0; t4 < 4; t4++) {
            frag8 ak0 = *(const frag8*)&Ks[cur][(t4 * 16 + l16) * 64 + ((quad ^ fsw) * 8)];
            frag8 ak1 = *(const frag8*)&Ks[cur][(t4 * 16 + l16) * 64 + (((quad + 4) ^ fsw) * 8)];
            #pragma unroll
            for (int half = 0; half < 2; half++) {
                f32x4 a = z4;
                a = __builtin_amdgcn_mfma_f32_16x16x32_bf16(ak0, aq[half][0], a, 0, 0, 0);
                a = __builtin_amdgcn_mfma_f32_16x16x32_bf16(ak1, aq[half][1], a, 0, 0, 0);
                #pragma unroll
                for (int r = 0; r < 4; r++) p[half][t4][r] = a[r];
            }
        }

        // fixed-reference exp (no-max softmax); native packed bf16 cvt, b64 store
        // Pl col XOR-swizzled per row: psw = (row&7)*8 shorts
        #pragma unroll
        for (int half = 0; half < 2; half++) {
            const int row = prow + half * 16;
            const int psw = (row & 7) * 8;
            #pragma unroll
            for (int t4 = 0; t4 < 4; t4++) {
                float e0 = exp2f(fmaf(p[half][t4][0], scl, gq[half] * gk4[t4][0]));
                float e1 = exp2f(fmaf(p[half][t4][1], scl, gq[half] * gk4[t4][1]));
                float e2 = exp2f(fmaf(p[half][t4][2], scl, gq[half] * gk4[t4][2]));
                float e3 = exp2f(fmaf(p[half][t4][3], scl, gq[half] * gk4[t4][3]));
                l_run[half] += (e0 + e1) + (e2 + e3);
                unsigned lo, hi;
                asm("v_cvt_pk_bf16_f32 %0, %1, %2" : "=v"(lo) : "v"(e0), "v"(e1));
                asm("v_cvt_pk_bf16_f32 %0, %1, %2" : "=v"(hi) : "v"(e2), "v"(e3));
                u32x2 w = {lo, hi};
                *(u32x2*)&Pl[row * LSTR + ((t4 * 16 + quad * 4) ^ psw)] = w;
            }
        }

        // O += P.V  (P rows wave-private; A-operand read, same XOR swizzle)
        frag8 ap[2][2];
        #pragma unroll
        for (int half = 0; half < 2; half++) {
            const int row = prow + half * 16;
            const int psw = (row & 7) * 8;
            #pragma unroll
            for (int kc = 0; kc < 2; kc++)
                ap[half][kc] = *(const frag8*)&Pl[row * LSTR + ((kc * 32 + quad * 8) ^ psw)];
        }
        #pragma unroll
        for (int d = 0; d < 4; d++) {
            frag8 av0 = *(const frag8*)&Vt[cur][(d * 16 + l16) * 64 + ((quad ^ fsw) * 8)];
            frag8 av1 = *(const frag8*)&Vt[cur][(d * 16 + l16) * 64 + (((quad + 4) ^ fsw) * 8)];
            #pragma unroll
            for (int half = 0; half < 2; half++) {
                o_acc[half][d] = __builtin_amdgcn_mfma_f32_16x16x32_bf16(ap[half][0], av0, o_acc[half][d], 0, 0, 0);
                o_acc[half][d] = __builtin_amdgcn_mfma_f32_16x16x32_bf16(ap[half][1], av1, o_acc[half][d], 0, 0, 0);
            }
        }
        __syncthreads();   // all waves done with buf[cur]; prefetch into buf[cur^1] drained
    }

    // epilogue: l_run[half] is partial sum for q = half*16+l16 over this lane's k subset;
    // full l = sum over the 4 quads sharing l16
    #pragma unroll
    for (int half = 0; half < 2; half++) {
        float l = l_run[half];
        l += __shfl_xor(l, 16);
        l += __shfl_xor(l, 32);
        #pragma unroll
        for (int r = 0; r < 4; r++) {
            float lq = __shfl(l, (lane & 48) | (quad * 4 + r));   // l for q = half*16 + quad*4 + r
            float inv_l = 1.0f / lq;
            int row = qt * 128 + wave * 32 + half * 16 + quad * 4 + r;
            #pragma unroll
            for (int d = 0; d < 4; d++)
                out[(size_t)(b * NTOK + row) * HIDDEN + h * HDIM + d * 16 + l16]
                    = f2bs(o_acc[half][d][r] * inv_l);
        }
    }
}

// ---------------------------------------------------------------- launch
extern "C" void kernel_launch(void* const* d_in, const int* in_sizes, int n_in,
                              void* d_out, int out_size, void* d_ws, size_t ws_size,
                              hipStream_t stream)
{
    const float* feat   = (const float*)d_in[0];
    const float* I      = (const float*)d_in[1];
    const float* proj_w = (const float*)d_in[2];
    const float* proj_b = (const float*)d_in[3];
    const float* wq     = (const float*)d_in[4];
    const float* bq     = (const float*)d_in[5];
    const float* wk     = (const float*)d_in[6];
    const float* bk     = (const float*)d_in[7];
    const float* wv     = (const float*)d_in[8];
    const float* bv     = (const float*)d_in[9];
    const float* wo     = (const float*)d_in[10];
    const float* bo     = (const float*)d_in[11];
    const float* lam    = (const float*)d_in[12];
    float* out = (float*)d_out;

    short* wtqkv = (short*)d_ws;
    short* wto   = wtqkv + (size_t)3 * HIDDEN * HIDDEN;
    short* wtp   = wto   + (size_t)HIDDEN * HIDDEN;
    short* tokens= wtp   + (size_t)HIDDEN * CIN;
    short* qbuf  = tokens+ (size_t)M_ALL * HIDDEN;
    short* featT = qbuf;                               // [8][1024][256] = 2.10M shorts
    float* pebuf = (float*)(qbuf + (size_t)2097152);   // PE table f32 (3.1MB); dead after step 2
    short* vTb   = tokens;
    short* kbuf  = (short*)d_out;
    short* vbuf  = kbuf + (size_t)M_ALL * HIDDEN;
    float* gbuf  = (float*)wtp;   // wtp dead after step 2; g (32KB) written step 4, read step 5

    // 1. prep: proj_w transpose + feat transpose + PE table
    prep_all<<<816, 256, 0, stream>>>(proj_w, feat, wtp, featT, pebuf);
    // 2. fused: tokens GEMM (+bias+PE-table) || wq/wk/wv/wo transposes
    tokens_wprep<<<1344, 256, 0, stream>>>(featT, wtp, proj_b, pebuf, tokens,
                                           wq, wk, wv, wo, wtqkv);
    // 3. fused QKV (128x128 tiles, double-buffered BK=32, 1152 blocks)
    gemm_mfma128<<<dim3(64, 6, 3), 256, 0, stream>>>(tokens, wtqkv, (long)HIDDEN * HIDDEN,
                                                     bq, bk, bv,
                                                     qbuf, kbuf, vbuf, HIDDEN);
    // 4. V transpose + gauss-weight precompute (extra y-slice)
    transpose_v<<<dim3(16, 97), 256, 0, stream>>>(vbuf, vTb, I, gbuf);
    // 5. attention (v6: Pl XOR swizzle, out in-place into qbuf)
    attn_mfma<<<768, 256, 0, stream>>>(qbuf, kbuf, vTb, gbuf, lam, qbuf);
    // 6. final projection (f32 out, 64x128 tiles)
    gemm_mfma64f<<<dim3(128, 6), 256, 0, stream>>>(qbuf, wto, bo, out, HIDDEN);
}

// Round 17
// 223.138 us; speedup vs baseline: 1.0667x; 1.0667x over previous
//
#include <hip/hip_runtime.h>
#include <hip/hip_bf16.h>
#include <math.h>

#define HIDDEN 768
#define NHEADS 12
#define HDIM   64
#define NTOK   1024   // 32*32
#define BATCH  8
#define CIN    256
#define M_ALL  (BATCH * NTOK)   // 8192
#define LSTR   72               // padded stride for P (register-sourced writes)

typedef __hip_bfloat16 bf16;
typedef short frag8 __attribute__((ext_vector_type(8)));   // 8 bf16 = 4 VGPRs
typedef short s16x4 __attribute__((ext_vector_type(4)));
typedef unsigned int u32x2 __attribute__((ext_vector_type(2)));
typedef float f32x4 __attribute__((ext_vector_type(4)));

#define GL2LDS(gp, lp) \
    __builtin_amdgcn_global_load_lds((const __attribute__((address_space(1))) void*)(gp), \
                                     (__attribute__((address_space(3))) void*)(lp), 16, 0, 0)

__device__ __forceinline__ short f2bs(float x){
    union { bf16 h; short s; } u; u.h = __float2bfloat16(x); return u.s;
}

// Gaussian weight (inference buffers mu=0 sigma=1)
__device__ __forceinline__ float gaussw(float x){
    float x2 = x * x;
    return (__expf(-x2 / 0.50001f) + __expf(-x2 / 2.00001f) + __expf(-x2 / 8.00001f)) * (1.0f / 3.0f);
}

// ------------------------------------------------------------ prep kernel
// blocks [0,48): proj_w transpose (256x768 -> wtp[768][256])
// blocks [48,560): feat transpose per batch ([256][1024] -> featT[b][1024][256])
// blocks [560,816): PE table precompute (1024x768 f32) — hoists expf/sinf/cosf
//                   out of the tokens-GEMM epilogue. Same math as before.
__global__ __launch_bounds__(256) void prep_all(
    const float* __restrict__ proj_w, const float* __restrict__ feat,
    short* __restrict__ wtp, short* __restrict__ featT, float* __restrict__ pe)
{
    const int blk = blockIdx.x;
    const int tid = threadIdx.x;
    if (blk >= 560) {
        const float kfac = -9.210340371976184f / 768.0f;  // -ln(10000)/HIDDEN
        int e0 = (blk - 560) * 3072 + tid;
        #pragma unroll
        for (int it = 0; it < 12; it++) {
            int e = e0 + it * 256;
            int n = e / 768;
            int d = e - n * 768;
            float ang = (float)n * expf((float)(2 * (d >> 1)) * kfac);
            pe[e] = (d & 1) ? cosf(ang) : sinf(ang);
        }
        return;
    }
    __shared__ short t[64][65];
    const float* W; short* WT; int K, N, k0, n0;
    if (blk < 48) {
        W = proj_w; WT = wtp;
        K = CIN; N = HIDDEN; k0 = (blk / 12) * 64; n0 = (blk % 12) * 64;
    } else {
        int rem = blk - 48;               // 512 = 8 b x 64 (4x16)
        int b = rem / 64; rem %= 64;
        W = feat + (size_t)b * CIN * NTOK; WT = featT + (size_t)b * NTOK * CIN;
        K = CIN; N = NTOK; k0 = (rem / 16) * 64; n0 = (rem % 16) * 64;
    }
    #pragma unroll
    for (int it = 0; it < 16; it++) {
        int e = tid + 256 * it;
        int kk = e / 64, nn = e % 64;
        t[kk][nn] = f2bs(W[(size_t)(k0 + kk) * N + n0 + nn]);
    }
    __syncthreads();
    #pragma unroll
    for (int it = 0; it < 16; it++) {
        int e = tid + 256 * it;
        int nn = e / 64, kk = e % 64;
        WT[(size_t)(n0 + nn) * K + k0 + kk] = t[kk][nn];
    }
}

// ------------------------------------------------------------ fused tokens GEMM + weight transposes
// blocks [0,768): tokens = featT @ wtp^T + bias + PE-table (64x128 tiles, K=256)
// blocks [768,1344): wq/wk/wv/wo transposes (consumed only by step 3 -> safe to
//   overlap with the tokens GEMM; block-level independence, no new sync edges)
__global__ __launch_bounds__(256) void tokens_wprep(
    const short* __restrict__ A, const short* __restrict__ WT,
    const float* __restrict__ bias, const float* __restrict__ pe,
    short* __restrict__ outv,
    const float* __restrict__ wq, const float* __restrict__ wk,
    const float* __restrict__ wv, const float* __restrict__ wo,
    short* __restrict__ wtqkv)
{
    const int blk = blockIdx.x;
    const int tid = threadIdx.x;
    if (blk >= 768) {
        __shared__ short t[64][65];
        int bw = blk - 768;
        int p = bw / 144, rem = bw % 144;
        const float* srcs[4] = {wq, wk, wv, wo};
        const float* W = srcs[p];
        short* WTo = wtqkv + (size_t)p * HIDDEN * HIDDEN;
        int k0 = (rem / 12) * 64, n0 = (rem % 12) * 64;
        #pragma unroll
        for (int it = 0; it < 16; it++) {
            int e = tid + 256 * it;
            int kk = e / 64, nn = e % 64;
            t[kk][nn] = f2bs(W[(size_t)(k0 + kk) * HIDDEN + n0 + nn]);
        }
        __syncthreads();
        #pragma unroll
        for (int it = 0; it < 16; it++) {
            int e = tid + 256 * it;
            int nn = e / 64, kk = e % 64;
            WTo[(size_t)(n0 + nn) * HIDDEN + k0 + kk] = t[kk][nn];
        }
        return;
    }
    __shared__ short Al[64 * 32];
    __shared__ short Bl[128 * 32];
    const int m0   = (blk & 127) * 64;
    const int n0   = (blk >> 7) * 128;
    const int lane = tid & 63, wid = tid >> 6;
    const int wn   = wid * 32;
    const int l16  = lane & 15, quad = lane >> 4;

    const int sr  = lane >> 2;
    const int ssg = (lane & 3) ^ ((sr >> 1) & 3);
    const int fsw = (l16 >> 1) & 3;

    const f32x4 z4 = {0.f, 0.f, 0.f, 0.f};
    f32x4 acc[4][2];
    #pragma unroll
    for (int i = 0; i < 4; i++)
        #pragma unroll
        for (int j = 0; j < 2; j++) acc[i][j] = z4;

    const int K = CIN;
    for (int k0 = 0; k0 < K; k0 += 32) {
        GL2LDS(A + (size_t)(m0 + wid * 16 + sr) * K + k0 + ssg * 8, &Al[(wid * 16) * 32]);
        #pragma unroll
        for (int t = 0; t < 2; t++) {
            int rbase = wid * 32 + t * 16;
            GL2LDS(WT + (size_t)(n0 + rbase + sr) * K + k0 + ssg * 8, &Bl[rbase * 32]);
        }
        __syncthreads();
        frag8 af[4], bfr[2];
        #pragma unroll
        for (int i = 0; i < 4; i++)
            af[i]  = *(const frag8*)&Al[(i * 16 + l16) * 32 + ((quad ^ fsw) * 8)];
        #pragma unroll
        for (int j = 0; j < 2; j++)
            bfr[j] = *(const frag8*)&Bl[(wn + j * 16 + l16) * 32 + ((quad ^ fsw) * 8)];
        #pragma unroll
        for (int i = 0; i < 4; i++)
            #pragma unroll
            for (int j = 0; j < 2; j++)
                acc[i][j] = __builtin_amdgcn_mfma_f32_16x16x32_bf16(af[i], bfr[j], acc[i][j], 0, 0, 0);
        __syncthreads();
    }

    #pragma unroll
    for (int i = 0; i < 4; i++) {
        #pragma unroll
        for (int r = 0; r < 4; r++) {
            int m = m0 + i * 16 + quad * 4 + r;
            int n_tok = m & (NTOK - 1);
            #pragma unroll
            for (int j = 0; j < 2; j++) {
                int col = n0 + wn + j * 16 + l16;
                float val = acc[i][j][r] + bias[col] + pe[n_tok * HIDDEN + col];
                outv[(size_t)m * HIDDEN + col] = f2bs(val);
            }
        }
    }
}

// ------------------------------------------------------------ V transpose (bf16 -> bf16)
// v [8192][768] -> vT [B*NH][64][1024]   (vT[bh][d][n])
// extra blocks (blockIdx.y == 96): precompute gauss weights g[b][n] from I
__global__ __launch_bounds__(256) void transpose_v(
    const short* __restrict__ v, short* __restrict__ vT,
    const float* __restrict__ I, float* __restrict__ g)
{
    if (blockIdx.y == BATCH * NHEADS) {
        int idx = blockIdx.x * 512 + threadIdx.x * 2;
        g[idx]     = gaussw(I[idx]);
        g[idx + 1] = gaussw(I[idx + 1]);
        return;
    }
    __shared__ short t[64][65];
    const int nt = blockIdx.x;
    const int bh = blockIdx.y;
    const int b = bh / NHEADS, h = bh % NHEADS;
    const int tid = threadIdx.x;
    #pragma unroll
    for (int it = 0; it < 16; it++) {
        int e = tid + 256 * it;
        int rr = e / 64, cc = e % 64;
        t[rr][cc] = v[(size_t)(b * NTOK + nt * 64 + rr) * HIDDEN + h * HDIM + cc];
    }
    __syncthreads();
    #pragma unroll
    for (int it = 0; it < 16; it++) {
        int e = tid + 256 * it;
        int c2 = e / 64, r2 = e % 64;
        vT[((size_t)bh * HDIM + c2) * NTOK + nt * 64 + r2] = t[r2][c2];
    }
}

// ------------------------------------------------------------ MFMA GEMM 128x128 (QKV)
// BK=32, DOUBLE-BUFFERED (attn-v5 sync pattern, verified round 12):
// prologue-stage tile 0 -> loop { prefetch ks+1 into buf^1; compute buf; ONE
// __syncthreads }. Halves barrier count (48 -> 24) and overlaps staging with
// compute. LDS: 2 x (8KB A + 8KB B) = 32 KB.
__global__ __launch_bounds__(256) void gemm_mfma128(
    const short* __restrict__ A, const short* __restrict__ WT0, long wt_z,
    const float* __restrict__ b0, const float* __restrict__ b1, const float* __restrict__ b2,
    short* o0, short* o1, short* o2, int K)
{
    __shared__ short Al[2][128 * 32];
    __shared__ short Bl[2][128 * 32];
    const int z = blockIdx.z;
    const short* WT  = WT0 + (size_t)z * wt_z;
    const float* bias = (z == 0) ? b0 : (z == 1) ? b1 : b2;
    short* outv       = (z == 0) ? o0 : (z == 1) ? o1 : o2;

    const int tid  = threadIdx.x;
    const int m0   = blockIdx.x * 128;
    const int n0   = blockIdx.y * 128;
    const int lane = tid & 63, wid = tid >> 6;
    const int wm   = (wid >> 1) * 64, wn = (wid & 1) * 64;
    const int l16  = lane & 15, quad = lane >> 4;

    const int sr  = lane >> 2;
    const int ssg = (lane & 3) ^ ((sr >> 1) & 3);
    const int fsw = (l16 >> 1) & 3;

    const f32x4 z4 = {0.f, 0.f, 0.f, 0.f};
    f32x4 acc[4][4];
    #pragma unroll
    for (int i = 0; i < 4; i++)
        #pragma unroll
        for (int j = 0; j < 4; j++) acc[i][j] = z4;

    // prologue: stage K-step 0 into buf 0
    #pragma unroll
    for (int t = 0; t < 2; t++) {
        int rbase = wid * 32 + t * 16;
        int r = rbase + sr;
        GL2LDS(A  + (size_t)(m0 + r) * K + ssg * 8, &Al[0][rbase * 32]);
        GL2LDS(WT + (size_t)(n0 + r) * K + ssg * 8, &Bl[0][rbase * 32]);
    }
    __syncthreads();

    const int NSTEP = K / 32;
    for (int ks = 0; ks < NSTEP; ks++) {
        const int cur = ks & 1;
        // prefetch next K-step into the other buffer (overlaps compute below)
        if (ks < NSTEP - 1) {
            int k0n = (ks + 1) * 32;
            #pragma unroll
            for (int t = 0; t < 2; t++) {
                int rbase = wid * 32 + t * 16;
                int r = rbase + sr;
                GL2LDS(A  + (size_t)(m0 + r) * K + k0n + ssg * 8, &Al[cur ^ 1][rbase * 32]);
                GL2LDS(WT + (size_t)(n0 + r) * K + k0n + ssg * 8, &Bl[cur ^ 1][rbase * 32]);
            }
        }
        frag8 af[4], bfr[4];
        #pragma unroll
        for (int i = 0; i < 4; i++)
            af[i]  = *(const frag8*)&Al[cur][(wm + i * 16 + l16) * 32 + ((quad ^ fsw) * 8)];
        #pragma unroll
        for (int j = 0; j < 4; j++)
            bfr[j] = *(const frag8*)&Bl[cur][(wn + j * 16 + l16) * 32 + ((quad ^ fsw) * 8)];
        #pragma unroll
        for (int i = 0; i < 4; i++)
            #pragma unroll
            for (int j = 0; j < 4; j++)
                acc[i][j] = __builtin_amdgcn_mfma_f32_16x16x32_bf16(af[i], bfr[j], acc[i][j], 0, 0, 0);
        __syncthreads();   // all waves done reading buf[cur]; prefetch into buf^1 drained
    }

    #pragma unroll
    for (int i = 0; i < 4; i++) {
        #pragma unroll
        for (int r = 0; r < 4; r++) {
            int m = m0 + wm + i * 16 + quad * 4 + r;
            #pragma unroll
            for (int j = 0; j < 4; j++) {
                int col = n0 + wn + j * 16 + l16;
                outv[(size_t)m * HIDDEN + col] = f2bs(acc[i][j][r] + bias[col]);
            }
        }
    }
}

// ------------------------------------------------------------ MFMA GEMM 64x128 (final projection)
// out f32 = acc + bias
__global__ __launch_bounds__(256) void gemm_mfma64f(
    const short* __restrict__ A, const short* __restrict__ WT,
    const float* __restrict__ bias, float* __restrict__ outv, int K)
{
    __shared__ short Al[64 * 32];
    __shared__ short Bl[128 * 32];
    const int tid  = threadIdx.x;
    const int m0   = blockIdx.x * 64;
    const int n0   = blockIdx.y * 128;
    const int lane = tid & 63, wid = tid >> 6;
    const int wn   = wid * 32;
    const int l16  = lane & 15, quad = lane >> 4;

    const int sr  = lane >> 2;
    const int ssg = (lane & 3) ^ ((sr >> 1) & 3);
    const int fsw = (l16 >> 1) & 3;

    const f32x4 z4 = {0.f, 0.f, 0.f, 0.f};
    f32x4 acc[4][2];
    #pragma unroll
    for (int i = 0; i < 4; i++)
        #pragma unroll
        for (int j = 0; j < 2; j++) acc[i][j] = z4;

    for (int k0 = 0; k0 < K; k0 += 32) {
        GL2LDS(A + (size_t)(m0 + wid * 16 + sr) * K + k0 + ssg * 8, &Al[(wid * 16) * 32]);
        #pragma unroll
        for (int t = 0; t < 2; t++) {
            int rbase = wid * 32 + t * 16;
            GL2LDS(WT + (size_t)(n0 + rbase + sr) * K + k0 + ssg * 8, &Bl[rbase * 32]);
        }
        __syncthreads();
        frag8 af[4], bfr[2];
        #pragma unroll
        for (int i = 0; i < 4; i++)
            af[i]  = *(const frag8*)&Al[(i * 16 + l16) * 32 + ((quad ^ fsw) * 8)];
        #pragma unroll
        for (int j = 0; j < 2; j++)
            bfr[j] = *(const frag8*)&Bl[(wn + j * 16 + l16) * 32 + ((quad ^ fsw) * 8)];
        #pragma unroll
        for (int i = 0; i < 4; i++)
            #pragma unroll
            for (int j = 0; j < 2; j++)
                acc[i][j] = __builtin_amdgcn_mfma_f32_16x16x32_bf16(af[i], bfr[j], acc[i][j], 0, 0, 0);
        __syncthreads();
    }

    #pragma unroll
    for (int i = 0; i < 4; i++) {
        #pragma unroll
        for (int r = 0; r < 4; r++) {
            int m = m0 + i * 16 + quad * 4 + r;
            #pragma unroll
            for (int j = 0; j < 2; j++) {
                int col = n0 + wn + j * 16 + l16;
                outv[(size_t)m * HIDDEN + col] = acc[i][j][r] + bias[col];
            }
        }
    }
}

// ------------------------------------------------------------- MFMA flash attention (v5, verified)
// K/V double-buffered via GL2LDS, gk4 global loads at tile-top (before
// prefetch), cvt_pk P conversion. Pl at LSTR=72 is inherently row-staggered
// (4-bank step/row) -> its accesses are a free 2-way alias; do NOT add an XOR
// swizzle on top (round-16: 6x conflict blowup).
//  LDS: P 18432 + 2x8192 (K) + 2x8192 (V) = 51200 B -> 3 blocks/CU.
__global__ __launch_bounds__(256, 3) void attn_mfma(
    const short* __restrict__ q, const short* __restrict__ k, const short* __restrict__ vT,
    const float* __restrict__ g, const float* __restrict__ lam_p, short* __restrict__ out)
{
    __shared__ short Pl[128 * LSTR];   // P tile, wave-private rows, padded stride
    __shared__ short Ks[2][64 * 64];
    __shared__ short Vt[2][64 * 64];

    const int tid  = threadIdx.x;
    const int lin  = blockIdx.x;
    const int xcd  = lin & 7, slot = lin >> 3;
    const int b    = xcd;
    const int h    = slot >> 3;
    const int qt   = slot & 7;
    const float L2E  = 1.4426950408889634f;
    const float lam2 = lam_p[0] * L2E;
    const float scl  = 0.125f * L2E;
    const int lane = tid & 63, wave = tid >> 6;
    const int l16  = lane & 15, quad = lane >> 4;

    const int sr   = lane >> 3;          // staging row within 8-row group
    const int slin = lane & 7;           // dest 16B segment
    const int ssg  = slin ^ sr;          // swizzled source segment
    const int fsw  = l16 & 7;            // frag-read swizzle

    const size_t kb  = (size_t)b * NTOK * HIDDEN + h * HDIM;
    const size_t vtb = (size_t)(b * NHEADS + h) * HDIM * NTOK;
    const float* gk  = g + b * NTOK;

    // Q fragments direct from global (B-operand: col = q row, kdim contiguous)
    frag8 aq[2][2];
    #pragma unroll
    for (int half = 0; half < 2; half++)
        #pragma unroll
        for (int kc = 0; kc < 2; kc++)
            aq[half][kc] = *(const frag8*)&q[(size_t)(b * NTOK + qt * 128 + wave * 32 + half * 16 + l16) * HIDDEN
                                             + h * HDIM + kc * 32 + quad * 8];
    // q-side gaussian (x lam2), one per half (q = half*16 + l16)
    float gq[2];
    #pragma unroll
    for (int half = 0; half < 2; half++)
        gq[half] = lam2 * gk[qt * 128 + wave * 32 + half * 16 + l16];

    // prologue: stage tile 0 into buf 0
    #pragma unroll
    for (int t = 0; t < 2; t++) {
        int rbase = wave * 16 + t * 8;
        int r = rbase + sr;
        GL2LDS(k  + kb  + (size_t)r * HIDDEN + ssg * 8,  &Ks[0][rbase * 64]);
        GL2LDS(vT + vtb + (size_t)r * NTOK + ssg * 8,    &Vt[0][rbase * 64]);
    }
    __syncthreads();

    const f32x4 z4 = {0.f, 0.f, 0.f, 0.f};
    f32x4 o_acc[2][4];
    #pragma unroll
    for (int half = 0; half < 2; half++)
        #pragma unroll
        for (int d = 0; d < 4; d++) o_acc[half][d] = z4;
    float l_run[2] = {0.f, 0.f};

    for (int jt = 0; jt < 16; jt++) {
        const int cur = jt & 1;
        // k-side gaussian for THIS tile, issued FIRST: the exp-phase consumption
        // then needs only vmcnt(4) (the 4 newer GL2LDS below stay in flight).
        f32x4 gk4[4];
        #pragma unroll
        for (int t4 = 0; t4 < 4; t4++)
            gk4[t4] = *(const f32x4*)&gk[jt * 64 + t4 * 16 + quad * 4];
        __builtin_amdgcn_sched_barrier(0);   // pin: g-loads issue before prefetch
        // prefetch next tile into the other buffer (overlaps with compute below)
        if (jt < 15) {
            #pragma unroll
            for (int t = 0; t < 2; t++) {
                int rbase = wave * 16 + t * 8;
                int r = rbase + sr;
                GL2LDS(k  + kb  + (size_t)((jt + 1) * 64 + r) * HIDDEN + ssg * 8, &Ks[cur ^ 1][rbase * 64]);
                GL2LDS(vT + vtb + (size_t)r * NTOK + (jt + 1) * 64 + ssg * 8,     &Vt[cur ^ 1][rbase * 64]);
            }
        }

        // S^T = K.Q^T : lane holds k = t4*16 + quad*4 + r, q = half*16 + l16
        float p[2][4][4];
        #pragma unroll
        for (int t4 = 0; t4 < 4; t4++) {
            frag8 ak0 = *(const frag8*)&Ks[cur][(t4 * 16 + l16) * 64 + ((quad ^ fsw) * 8)];
            frag8 ak1 = *(const frag8*)&Ks[cur][(t4 * 16 + l16) * 64 + (((quad + 4) ^ fsw) * 8)];
            #pragma unroll
            for (int half = 0; half < 2; half++) {
                f32x4 a = z4;
                a = __builtin_amdgcn_mfma_f32_16x16x32_bf16(ak0, aq[half][0], a, 0, 0, 0);
                a = __builtin_amdgcn_mfma_f32_16x16x32_bf16(ak1, aq[half][1], a, 0, 0, 0);
                #pragma unroll
                for (int r = 0; r < 4; r++) p[half][t4][r] = a[r];
            }
        }

        // fixed-reference exp (no-max softmax); native packed bf16 cvt, b64 store
        #pragma unroll
        for (int half = 0; half < 2; half++)
            #pragma unroll
            for (int t4 = 0; t4 < 4; t4++) {
                float e0 = exp2f(fmaf(p[half][t4][0], scl, gq[half] * gk4[t4][0]));
                float e1 = exp2f(fmaf(p[half][t4][1], scl, gq[half] * gk4[t4][1]));
                float e2 = exp2f(fmaf(p[half][t4][2], scl, gq[half] * gk4[t4][2]));
                float e3 = exp2f(fmaf(p[half][t4][3], scl, gq[half] * gk4[t4][3]));
                l_run[half] += (e0 + e1) + (e2 + e3);
                unsigned lo, hi;
                asm("v_cvt_pk_bf16_f32 %0, %1, %2" : "=v"(lo) : "v"(e0), "v"(e1));
                asm("v_cvt_pk_bf16_f32 %0, %1, %2" : "=v"(hi) : "v"(e2), "v"(e3));
                u32x2 w = {lo, hi};
                *(u32x2*)&Pl[(wave * 32 + half * 16 + l16) * LSTR + t4 * 16 + quad * 4] = w;
            }

        // O += P.V  (P rows wave-private; A-operand read, padded stride)
        frag8 ap[2][2];
        #pragma unroll
        for (int half = 0; half < 2; half++)
            #pragma unroll
            for (int kc = 0; kc < 2; kc++)
                ap[half][kc] = *(const frag8*)&Pl[(wave * 32 + half * 16 + l16) * LSTR + kc * 32 + quad * 8];
        #pragma unroll
        for (int d = 0; d < 4; d++) {
            frag8 av0 = *(const frag8*)&Vt[cur][(d * 16 + l16) * 64 + ((quad ^ fsw) * 8)];
            frag8 av1 = *(const frag8*)&Vt[cur][(d * 16 + l16) * 64 + (((quad + 4) ^ fsw) * 8)];
            #pragma unroll
            for (int half = 0; half < 2; half++) {
                o_acc[half][d] = __builtin_amdgcn_mfma_f32_16x16x32_bf16(ap[half][0], av0, o_acc[half][d], 0, 0, 0);
                o_acc[half][d] = __builtin_amdgcn_mfma_f32_16x16x32_bf16(ap[half][1], av1, o_acc[half][d], 0, 0, 0);
            }
        }
        __syncthreads();   // all waves done with buf[cur]; prefetch into buf[cur^1] drained
    }

    // epilogue: l_run[half] is partial sum for q = half*16+l16 over this lane's k subset;
    // full l = sum over the 4 quads sharing l16
    #pragma unroll
    for (int half = 0; half < 2; half++) {
        float l = l_run[half];
        l += __shfl_xor(l, 16);
        l += __shfl_xor(l, 32);
        #pragma unroll
        for (int r = 0; r < 4; r++) {
            float lq = __shfl(l, (lane & 48) | (quad * 4 + r));   // l for q = half*16 + quad*4 + r
            float inv_l = 1.0f / lq;
            int row = qt * 128 + wave * 32 + half * 16 + quad * 4 + r;
            #pragma unroll
            for (int d = 0; d < 4; d++)
                out[(size_t)(b * NTOK + row) * HIDDEN + h * HDIM + d * 16 + l16]
                    = f2bs(o_acc[half][d][r] * inv_l);
        }
    }
}

// ---------------------------------------------------------------- launch
extern "C" void kernel_launch(void* const* d_in, const int* in_sizes, int n_in,
                              void* d_out, int out_size, void* d_ws, size_t ws_size,
                              hipStream_t stream)
{
    const float* feat   = (const float*)d_in[0];
    const float* I      = (const float*)d_in[1];
    const float* proj_w = (const float*)d_in[2];
    const float* proj_b = (const float*)d_in[3];
    const float* wq     = (const float*)d_in[4];
    const float* bq     = (const float*)d_in[5];
    const float* wk     = (const float*)d_in[6];
    const float* bk     = (const float*)d_in[7];
    const float* wv     = (const float*)d_in[8];
    const float* bv     = (const float*)d_in[9];
    const float* wo     = (const float*)d_in[10];
    const float* bo     = (const float*)d_in[11];
    const float* lam    = (const float*)d_in[12];
    float* out = (float*)d_out;

    short* wtqkv = (short*)d_ws;
    short* wto   = wtqkv + (size_t)3 * HIDDEN * HIDDEN;
    short* wtp   = wto   + (size_t)HIDDEN * HIDDEN;
    short* tokens= wtp   + (size_t)HIDDEN * CIN;
    short* qbuf  = tokens+ (size_t)M_ALL * HIDDEN;
    short* featT = qbuf;                               // [8][1024][256] = 2.10M shorts
    float* pebuf = (float*)(qbuf + (size_t)2097152);   // PE table f32 (3.1MB); dead after step 2
    short* vTb   = tokens;
    short* kbuf  = (short*)d_out;
    short* vbuf  = kbuf + (size_t)M_ALL * HIDDEN;
    float* gbuf  = (float*)wtp;   // wtp dead after step 2; g (32KB) written step 4, read step 5

    // 1. prep: proj_w transpose + feat transpose + PE table
    prep_all<<<816, 256, 0, stream>>>(proj_w, feat, wtp, featT, pebuf);
    // 2. fused: tokens GEMM (+bias+PE-table) || wq/wk/wv/wo transposes
    tokens_wprep<<<1344, 256, 0, stream>>>(featT, wtp, proj_b, pebuf, tokens,
                                           wq, wk, wv, wo, wtqkv);
    // 3. fused QKV (128x128 tiles, double-buffered BK=32, 1152 blocks)
    gemm_mfma128<<<dim3(64, 6, 3), 256, 0, stream>>>(tokens, wtqkv, (long)HIDDEN * HIDDEN,
                                                     bq, bk, bv,
                                                     qbuf, kbuf, vbuf, HIDDEN);
    // 4. V transpose + gauss-weight precompute (extra y-slice)
    transpose_v<<<dim3(16, 97), 256, 0, stream>>>(vbuf, vTb, I, gbuf);
    // 5. attention (v5 verified, out in-place into qbuf)
    attn_mfma<<<768, 256, 0, stream>>>(qbuf, kbuf, vTb, gbuf, lam, qbuf);
    // 6. final projection (f32 out, 64x128 tiles)
    gemm_mfma64f<<<dim3(128, 6), 256, 0, stream>>>(qbuf, wto, bo, out, HIDDEN);
}